// Round 2
// 406.320 us; speedup vs baseline: 1.0700x; 1.0700x over previous
//
#include <hip/hip_runtime.h>
#include <hip/hip_bf16.h>
#include <stdint.h>

#define RES 512
#define CH  32
#define NP  3
#define NTEX (NP * RES * RES)                             // 786432 texels
#define NT2  (NTEX / 2)                                   // texel pairs
#define WS_BYTES ((size_t)NTEX * CH * sizeof(uint16_t))   // 48 MiB (bf16 ws)

typedef float vfloat4 __attribute__((ext_vector_type(4)));   // clang-native for NT store

static __device__ __forceinline__ uint16_t f2bf(float f) {
    union { float f; uint32_t u; } v; v.f = f;
    uint32_t u = v.u;
    uint32_t r = (u + 0x7fffu + ((u >> 16) & 1u)) >> 16;   // RNE
    return (uint16_t)r;
}

// ---------------------------------------------------------------------------
// Kernel 1: [3][C][R][R] fp32 -> [3][R][R][C] bf16, clipped to [-1,1].
// One thread per x-ADJACENT TEXEL PAIR: float2 source reads (512B contiguous
// per wave instruction), 128B contiguous bf16 write per thread.
// ---------------------------------------------------------------------------
__global__ __launch_bounds__(256) void k_transpose(const float* __restrict__ tri,
                                                   uint16_t* __restrict__ ws) {
    int t2 = blockIdx.x * 256 + threadIdx.x;
    if (t2 >= NT2) return;
    int xp = t2 & (RES / 2 - 1);          // x-pair index 0..255
    int y  = (t2 >> 8) & (RES - 1);
    int p  = t2 >> 17;
    int x  = xp * 2;
    const float* src = tri + (size_t)p * CH * RES * RES + (size_t)y * RES + x;
    uint32_t pa[16], pb[16];
#pragma unroll
    for (int i = 0; i < 16; ++i) {
        float2 f0 = *(const float2*)&src[(size_t)(2 * i + 0) * (RES * RES)];
        float2 f1 = *(const float2*)&src[(size_t)(2 * i + 1) * (RES * RES)];
        float a0 = fminf(1.f, fmaxf(-1.f, f0.x));
        float a1 = fminf(1.f, fmaxf(-1.f, f1.x));
        float b0 = fminf(1.f, fmaxf(-1.f, f0.y));
        float b1 = fminf(1.f, fmaxf(-1.f, f1.y));
        pa[i] = (uint32_t)f2bf(a0) | ((uint32_t)f2bf(a1) << 16);
        pb[i] = (uint32_t)f2bf(b0) | ((uint32_t)f2bf(b1) << 16);
    }
    // texel t = 2*t2 (p*R*R + y*R + x), pair is contiguous: 128 B per thread
    uint4* dst = (uint4*)(ws + (size_t)(2 * t2) * CH);
#pragma unroll
    for (int i = 0; i < 4; ++i)
        dst[i] = make_uint4(pa[4 * i], pa[4 * i + 1], pa[4 * i + 2], pa[4 * i + 3]);
#pragma unroll
    for (int i = 0; i < 4; ++i)
        dst[4 + i] = make_uint4(pb[4 * i], pb[4 * i + 1], pb[4 * i + 2], pb[4 * i + 3]);
}

// ---------------------------------------------------------------------------
// Kernel 2: gather, 4-LANE-COOPERATIVE. Lanes {4k..4k+3} handle one point;
// each lane owns one 16B chunk (8 channels) of the 64B texel vector. Every
// tap is a single dwordx4 per lane => a wave instruction touches 16 distinct
// cache lines (4 lanes coalesce per line) instead of 64 with thread-per-point.
// acc shrinks 32->8 fp32 => much lower VGPR, higher occupancy. Output:
// lane-contiguous 2KB wave segments, nontemporal (write-once 134MB output
// must not evict ws from L2).
// Projections (verified): p0 (cy,cx)  p1 (cz,cx)  p2 (cy,cz)
// ---------------------------------------------------------------------------
__global__ __launch_bounds__(256) void k_gather(const float* __restrict__ coords,
                                                const uint16_t* __restrict__ ws,
                                                float* __restrict__ out, int M) {
    int tid = threadIdx.x;
    int sub = tid & 3;                       // which 16B chunk: channels [8*sub, 8*sub+8)
    int m = blockIdx.x * 64 + (tid >> 2);
    if (m >= M) return;
    float cx = coords[3 * m + 0];
    float cy = coords[3 * m + 1];
    float cz = coords[3 * m + 2];

    float acc[8];
#pragma unroll
    for (int c = 0; c < 8; ++c) acc[c] = 0.f;

    float us[3] = {cy, cz, cy};
    float vs[3] = {cx, cx, cz};

#pragma unroll
    for (int p = 0; p < 3; ++p) {
        float px = (us[p] + 1.f) * (0.5f * (RES - 1));
        float py = (vs[p] + 1.f) * (0.5f * (RES - 1));
        float x0f = floorf(px), y0f = floorf(py);
        int x0 = (int)x0f, y0 = (int)y0f;
        float wx1 = px - x0f, wx0 = 1.f - wx1;
        float wy1 = py - y0f, wy0 = 1.f - wy1;
        int   xs[2]  = {x0, x0 + 1};
        int   ys[2]  = {y0, y0 + 1};
        float wxv[2] = {wx0, wx1};
        float wyv[2] = {wy0, wy1};
#pragma unroll
        for (int j = 0; j < 2; ++j) {
#pragma unroll
            for (int i = 0; i < 2; ++i) {
                int xi = xs[i], yi = ys[j];
                bool valid = (xi >= 0) & (xi < RES) & (yi >= 0) & (yi < RES);
                int xc = min(max(xi, 0), RES - 1);
                int yc = min(max(yi, 0), RES - 1);
                float w = valid ? (wxv[i] * wyv[j]) : 0.f;
                const uint4* tp = (const uint4*)(ws + (((size_t)p * RES + yc) * RES + xc) * CH
                                                 + (size_t)sub * 8);
                uint4 d = *tp;                               // ONE dwordx4 per tap
                uint32_t vv[4] = {d.x, d.y, d.z, d.w};
#pragma unroll
                for (int e = 0; e < 4; ++e) {
                    union { uint32_t u; float f; } lo, hi;
                    lo.u = vv[e] << 16;
                    hi.u = vv[e] & 0xffff0000u;
                    acc[2 * e + 0] += w * lo.f;
                    acc[2 * e + 1] += w * hi.f;
                }
            }
        }
    }

    vfloat4* dst = (vfloat4*)(out + (size_t)m * CH + (size_t)sub * 8);
    vfloat4 v0 = {acc[0], acc[1], acc[2], acc[3]};
    vfloat4 v1 = {acc[4], acc[5], acc[6], acc[7]};
    __builtin_nontemporal_store(v0, dst);
    __builtin_nontemporal_store(v1, dst + 1);
}

// ---------------------------------------------------------------------------
// Fallback (only if ws too small): gather straight from [3][C][R][R] fp32.
// ---------------------------------------------------------------------------
__global__ __launch_bounds__(256) void k_gather_direct(const float* __restrict__ coords,
                                                       const float* __restrict__ tri,
                                                       float* __restrict__ out, int M) {
    int m = blockIdx.x * 256 + threadIdx.x;
    if (m >= M) return;
    float cx = coords[3 * m + 0];
    float cy = coords[3 * m + 1];
    float cz = coords[3 * m + 2];
    float acc[CH];
#pragma unroll
    for (int c = 0; c < CH; ++c) acc[c] = 0.f;
    float us[3] = {cy, cz, cy};
    float vs[3] = {cx, cx, cz};
    for (int p = 0; p < 3; ++p) {
        float px = (us[p] + 1.f) * (0.5f * (RES - 1));
        float py = (vs[p] + 1.f) * (0.5f * (RES - 1));
        float x0f = floorf(px), y0f = floorf(py);
        int x0 = (int)x0f, y0 = (int)y0f;
        float wx1 = px - x0f, wx0 = 1.f - wx1;
        float wy1 = py - y0f, wy0 = 1.f - wy1;
        int   xs[2]  = {x0, x0 + 1};
        int   ys[2]  = {y0, y0 + 1};
        float wxv[2] = {wx0, wx1};
        float wyv[2] = {wy0, wy1};
        for (int j = 0; j < 2; ++j)
            for (int i = 0; i < 2; ++i) {
                int xi = xs[i], yi = ys[j];
                bool valid = (xi >= 0) & (xi < RES) & (yi >= 0) & (yi < RES);
                int xc = min(max(xi, 0), RES - 1);
                int yc = min(max(yi, 0), RES - 1);
                float w = valid ? (wxv[i] * wyv[j]) : 0.f;
                const float* base = tri + ((size_t)p * CH) * RES * RES + (size_t)yc * RES + xc;
#pragma unroll
                for (int c = 0; c < CH; ++c) {
                    float v = base[(size_t)c * RES * RES];
                    v = fminf(1.f, fmaxf(-1.f, v));
                    acc[c] += w * v;
                }
            }
    }
    float4* dst = (float4*)(out + (size_t)m * CH);
#pragma unroll
    for (int i = 0; i < 8; ++i)
        dst[i] = make_float4(acc[4 * i], acc[4 * i + 1], acc[4 * i + 2], acc[4 * i + 3]);
}

extern "C" void kernel_launch(void* const* d_in, const int* in_sizes, int n_in,
                              void* d_out, int out_size, void* d_ws, size_t ws_size,
                              hipStream_t stream) {
    const float* coords = (const float*)d_in[0];   // fp32 [M,3]
    const float* tri    = (const float*)d_in[1];   // fp32 [1,3,32,512,512]
    float* out          = (float*)d_out;           // fp32 [M,32]
    int M = in_sizes[0] / 3;

    if (ws_size >= WS_BYTES) {
        uint16_t* ws = (uint16_t*)d_ws;
        k_transpose<<<(NT2 + 255) / 256, 256, 0, stream>>>(tri, ws);
        k_gather<<<(M + 63) / 64, 256, 0, stream>>>(coords, ws, out, M);
    } else {
        k_gather_direct<<<(M + 255) / 256, 256, 0, stream>>>(coords, tri, out, M);
    }
}